// Round 1
// 131.069 us; speedup vs baseline: 1.0399x; 1.0399x over previous
//
#include <hip/hip_runtime.h>
#include <math.h>

#define S_ 2048
#define NH 8
#define DH 64
#define CSL 320       // R3 slots per row: cslot = j - (i&~31) + 256 in [0,320)
#define LP 72         // bf16 LDS row pitch: 144 B = 9*16 B -> b128-aligned

typedef __attribute__((ext_vector_type(8))) short short8;   // 8 x bf16 (4 VGPRs)
typedef __attribute__((ext_vector_type(4))) float f32x4;    // MFMA accumulator
typedef unsigned short ushort_t;

__device__ __forceinline__ short bf16r(float x) {   // RNE float->bf16
    union { float f; unsigned u; } v; v.f = x;
    unsigned r = v.u + 0x7fffu + ((v.u >> 16) & 1u);
    return (short)(r >> 16);
}
__device__ __forceinline__ float b2f(ushort_t h) {  // bf16->float
    union { float f; unsigned u; } v; v.u = ((unsigned)h) << 16; return v.f;
}

// ---------------------------------------------------------------------------
// Kernel 0: prep.  z<4: WT[n][k] = bf16(W[k][n]) (LDS-tiled 64x64).
// z==4: pos table bf16; rows 257..383 zero.  z==5: xb16 = bf16(x).
// ---------------------------------------------------------------------------
__global__ __launch_bounds__(256) void prep_kernel(
    const float* __restrict__ x,
    const float* __restrict__ Wq, const float* __restrict__ Wk,
    const float* __restrict__ Wv, const float* __restrict__ Wkr,
    ushort_t* __restrict__ WTq, ushort_t* __restrict__ WTk,
    ushort_t* __restrict__ WTv, ushort_t* __restrict__ WTkr,
    ushort_t* __restrict__ pos, ushort_t* __restrict__ xb16)
{
    const int widx = blockIdx.z;
    const int t = threadIdx.x;
    if (widx == 4) {
        const int base = blockIdx.y * 8 + blockIdx.x;    // 0..63
        const float C = -0.051905126482615036f;          // -log2(10000)/256
        const int f = t;
#pragma unroll
        for (int rep = 0; rep < 6; ++rep) {
            const int r = base + rep * 64;               // 0..383
            unsigned pk = 0;
            if (r <= 256) {
                float ang = (float)r * exp2f(C * (float)f);
                unsigned s = (unsigned)(ushort_t)bf16r(sinf(ang));
                unsigned c = (unsigned)(ushort_t)bf16r(cosf(ang));
                pk = s | (c << 16);
            }
            ((unsigned*)pos)[(size_t)r * 256 + f] = pk;
        }
        return;
    }
    if (widx == 5) {
        const int sub = blockIdx.y * 8 + blockIdx.x;     // 0..63
        const size_t base = (size_t)sub * 32768;
#pragma unroll
        for (int it = 0; it < 8; ++it) {
            const size_t idx = base + (size_t)it * 4096 + (size_t)t * 16;
            const float* src = &x[idx];
            ushort_t t16[16];
#pragma unroll
            for (int u = 0; u < 16; ++u) t16[u] = (ushort_t)bf16r(src[u]);
            *(short8*)&xb16[idx]     = *(short8*)&t16[0];
            *(short8*)&xb16[idx + 8] = *(short8*)&t16[8];
        }
        return;
    }
    const float* W = (widx == 0) ? Wq : (widx == 1) ? Wk : (widx == 2) ? Wv : Wkr;
    ushort_t* WT   = (widx == 0) ? WTq : (widx == 1) ? WTk : (widx == 2) ? WTv : WTkr;
    const int k0 = blockIdx.x * 64, n0 = blockIdx.y * 64;
    __shared__ __align__(16) ushort_t T[64][72];
    const int srow = t >> 2, sc0 = (t & 3) * 16;
    const float* src = &W[(size_t)(k0 + srow) * 512 + n0 + sc0];
#pragma unroll
    for (int u = 0; u < 16; ++u) T[sc0 + u][srow] = (ushort_t)bf16r(src[u]);
    __syncthreads();
    ushort_t* dst = &WT[(size_t)(n0 + srow) * 512 + k0 + sc0];
    *(short8*)dst       = *(const short8*)&T[srow][sc0];
    *(short8*)(dst + 8) = *(const short8*)&T[srow][sc0 + 8];
}

// ---------------------------------------------------------------------------
// Kernel 1: fused QKV (+krel) GEMM via bf16 MFMA.  Grid (32, 25).  R16 body.
// xlen-aware: q tiles with s0 >= xlen+256 are never read (dead rows ->
// vmean path); k tiles with s0 >= xlen+63 are never staged by attn.
// ---------------------------------------------------------------------------
__global__ __launch_bounds__(256) void qkv_gemm(
    const ushort_t* __restrict__ xb16,
    const ushort_t* __restrict__ WTq, const ushort_t* __restrict__ WTk,
    const ushort_t* __restrict__ WTv,
    const ushort_t* __restrict__ pos, const ushort_t* __restrict__ WTkr,
    const float* __restrict__ b_con, const float* __restrict__ b_rel,
    const float* __restrict__ bv, const int* __restrict__ xlen_p,
    ushort_t* __restrict__ qcon, ushort_t* __restrict__ qrel,
    ushort_t* __restrict__ kout, ushort_t* __restrict__ vT,
    ushort_t* __restrict__ krel)
{
    const int widx = blockIdx.y >> 3;
    const int tid = threadIdx.x, lane = tid & 63, w = tid >> 6;
    const int quad = lane >> 4, l16 = lane & 15;

    __shared__ __align__(16) ushort_t A_lds[128][40];
    __shared__ __align__(16) ushort_t B_lds[64][40];

    f32x4 acc[2][4];
#pragma unroll
    for (int mt = 0; mt < 2; ++mt)
#pragma unroll
        for (int nt = 0; nt < 4; ++nt) acc[mt][nt] = (f32x4){0.f, 0.f, 0.f, 0.f};

    const int arow = tid >> 1, ak0 = (tid & 1) * 16;
    const int brow = tid >> 2, bk0 = (tid & 3) * 8;

    if (widx < 2) {
        const int m0 = blockIdx.x * 128;
        // ---- xlen elision: rows are (b, s) = (m0>>11, m0&2047) ----
        {
            const int xl = xlen_p[m0 >> 11];
            const int s0 = m0 & 2047;
            if (widx == 0) { if (s0 >= xl + 256) return; }   // q rows dead
            else           { if (s0 >= xl + 63)  return; }   // k rows never staged
        }
        const int n0 = (blockIdx.y & 7) * 64;
        const ushort_t* WT = (widx == 0) ? WTq : WTk;
        const ushort_t* xrow = &xb16[(size_t)(m0 + arow) * 512 + ak0];
        const ushort_t* wrow = &WT[(size_t)(n0 + brow) * 512 + bk0];

        short8 pa0 = *(const short8*)xrow;
        short8 pa1 = *(const short8*)(xrow + 8);
        short8 pb  = *(const short8*)wrow;

#pragma unroll 1
        for (int k0 = 0; k0 < 512; k0 += 32) {
            __syncthreads();   // prev iter's MFMA LDS reads done
            *(short8*)&A_lds[arow][ak0]     = pa0;
            *(short8*)&A_lds[arow][ak0 + 8] = pa1;
            *(short8*)&B_lds[brow][bk0]     = pb;
            if (k0 < 480) {
                pa0 = *(const short8*)(xrow + k0 + 32);
                pa1 = *(const short8*)(xrow + k0 + 40);
                pb  = *(const short8*)(wrow + k0 + 32);
            }
            __syncthreads();
            short8 a0 = *(const short8*)&A_lds[w * 32 + l16][quad * 8];
            short8 a1 = *(const short8*)&A_lds[w * 32 + 16 + l16][quad * 8];
#pragma unroll
            for (int nt = 0; nt < 4; ++nt) {
                short8 bb = *(const short8*)&B_lds[nt * 16 + l16][quad * 8];
                acc[0][nt] = __builtin_amdgcn_mfma_f32_16x16x32_bf16(a0, bb, acc[0][nt], 0, 0, 0);
                acc[1][nt] = __builtin_amdgcn_mfma_f32_16x16x32_bf16(a1, bb, acc[1][nt], 0, 0, 0);
            }
        }

#pragma unroll
        for (int nt = 0; nt < 4; ++nt) {
            const int col = n0 + nt * 16 + l16;
            float bc = 0.f, br = 0.f;
            if (widx == 0) { bc = b_con[col]; br = b_rel[col]; }
#pragma unroll
            for (int mt = 0; mt < 2; ++mt) {
#pragma unroll
                for (int reg = 0; reg < 4; ++reg) {
                    const size_t m = (size_t)(m0 + w * 32 + mt * 16 + quad * 4 + reg);
                    const float val = acc[mt][nt][reg];
                    if (widx == 0) {
                        qcon[m * 512 + col] = (ushort_t)bf16r((val + bc) * 0.125f);
                        qrel[m * 512 + col] = (ushort_t)bf16r((val + br) * 0.125f);
                    } else {
                        kout[m * 512 + col] = (ushort_t)bf16r(val);
                    }
                }
            }
        }
    } else if (widx == 2) {
        // ---- V transposed mode: vT[d][j] = WTv[d] . x[j] + bv ----
        // (never elided: vmean needs the full 2048-col mean)
        const int vb = (blockIdx.y & 7) * 32 + blockIdx.x;   // 0..255
        const int m0d = (vb & 3) * 128;                      // d tile
        const int n0j = (vb >> 2) * 64;                      // seq tile
        const ushort_t* wrow = &WTv[(size_t)(m0d + arow) * 512 + ak0];
        const ushort_t* xrow = &xb16[(size_t)(n0j + brow) * 512 + bk0];

        short8 pa0 = *(const short8*)wrow;
        short8 pa1 = *(const short8*)(wrow + 8);
        short8 pb  = *(const short8*)xrow;

#pragma unroll 1
        for (int k0 = 0; k0 < 512; k0 += 32) {
            __syncthreads();
            *(short8*)&A_lds[arow][ak0]     = pa0;
            *(short8*)&A_lds[arow][ak0 + 8] = pa1;
            *(short8*)&B_lds[brow][bk0]     = pb;
            if (k0 < 480) {
                pa0 = *(const short8*)(wrow + k0 + 32);
                pa1 = *(const short8*)(wrow + k0 + 40);
                pb  = *(const short8*)(xrow + k0 + 32);
            }
            __syncthreads();
            short8 a0 = *(const short8*)&A_lds[w * 32 + l16][quad * 8];
            short8 a1 = *(const short8*)&A_lds[w * 32 + 16 + l16][quad * 8];
#pragma unroll
            for (int nt = 0; nt < 4; ++nt) {
                short8 bb = *(const short8*)&B_lds[nt * 16 + l16][quad * 8];
                acc[0][nt] = __builtin_amdgcn_mfma_f32_16x16x32_bf16(a0, bb, acc[0][nt], 0, 0, 0);
                acc[1][nt] = __builtin_amdgcn_mfma_f32_16x16x32_bf16(a1, bb, acc[1][nt], 0, 0, 0);
            }
        }

        const int b = n0j >> 11;
#pragma unroll
        for (int mt = 0; mt < 2; ++mt) {
#pragma unroll
            for (int reg = 0; reg < 4; ++reg) {
                const int d = m0d + w * 32 + mt * 16 + quad * 4 + reg;  // 0..511
                const int n = d >> 6, dd = d & 63;
                const float bvv = bv[d];
#pragma unroll
                for (int nt = 0; nt < 4; ++nt) {
                    const int s = (n0j + nt * 16 + l16) & 2047;
                    vT[((size_t)((b * NH + n) * 64 + dd)) * 2048 + s] =
                        (ushort_t)bf16r(acc[mt][nt][reg] + bvv);
                }
            }
        }
    } else {
        // ---- krel mode (by == 24): krel = pos @ Wkr ----
        if (blockIdx.x >= 24) return;
        const int m0 = (blockIdx.x >> 3) * 128;              // 0..255
        const int n0 = (blockIdx.x & 7) * 64;
        const ushort_t* prow = &pos[(size_t)(m0 + arow) * 512 + ak0];
        const ushort_t* wrow = &WTkr[(size_t)(n0 + brow) * 512 + bk0];

        short8 pa0 = *(const short8*)prow;
        short8 pa1 = *(const short8*)(prow + 8);
        short8 pb  = *(const short8*)wrow;

#pragma unroll 1
        for (int k0 = 0; k0 < 512; k0 += 32) {
            __syncthreads();
            *(short8*)&A_lds[arow][ak0]     = pa0;
            *(short8*)&A_lds[arow][ak0 + 8] = pa1;
            *(short8*)&B_lds[brow][bk0]     = pb;
            if (k0 < 480) {
                pa0 = *(const short8*)(prow + k0 + 32);
                pa1 = *(const short8*)(prow + k0 + 40);
                pb  = *(const short8*)(wrow + k0 + 32);
            }
            __syncthreads();
            short8 a0 = *(const short8*)&A_lds[w * 32 + l16][quad * 8];
            short8 a1 = *(const short8*)&A_lds[w * 32 + 16 + l16][quad * 8];
#pragma unroll
            for (int nt = 0; nt < 4; ++nt) {
                short8 bb = *(const short8*)&B_lds[nt * 16 + l16][quad * 8];
                acc[0][nt] = __builtin_amdgcn_mfma_f32_16x16x32_bf16(a0, bb, acc[0][nt], 0, 0, 0);
                acc[1][nt] = __builtin_amdgcn_mfma_f32_16x16x32_bf16(a1, bb, acc[1][nt], 0, 0, 0);
            }
        }

#pragma unroll
        for (int nt = 0; nt < 4; ++nt) {
            const int col = n0 + nt * 16 + l16;
#pragma unroll
            for (int mt = 0; mt < 2; ++mt)
#pragma unroll
                for (int reg = 0; reg < 4; ++reg) {
                    const size_t m = (size_t)(m0 + w * 32 + mt * 16 + quad * 4 + reg);
                    krel[m * 512 + col] = (ushort_t)bf16r(acc[mt][nt][reg]);
                }
        }
    }
}

// ---------------------------------------------------------------------------
// Kernel 3: rel GEMM, writing R in attention's consumption layout.
// xlen-aware: tiles whose 128 rows are all dead (i0 >= xlen+256) are never
// read by attn (dead blocks take the vmean fast path) -> skip.
// Grid (17,8,2): tile<16 = GEMM; tile==16 = vmean fold.
// ---------------------------------------------------------------------------
__global__ __launch_bounds__(256) void rel_gemm(
    const ushort_t* __restrict__ qrel, const ushort_t* __restrict__ krel,
    const ushort_t* __restrict__ vT, const int* __restrict__ xlen_p,
    ushort_t* __restrict__ R3, float* __restrict__ vmean)
{
    const int tile = blockIdx.x, n = blockIdx.y, b = blockIdx.z;
    const int tid = threadIdx.x, lane = tid & 63, w = tid >> 6;
    const int quad = lane >> 4, l16 = lane & 15;

    __shared__ __align__(16) ushort_t A_lds[128][LP];
    __shared__ __align__(16) ushort_t B_lds[64][LP];

    if (tile == 16) {
        // ---- vmean: rows (b*8+n)*64 + d of vT, mean over 2048 ----
        const int row = tid >> 2, seg = tid & 3;
        const ushort_t* src = &vT[((size_t)((b * NH + n) * 64 + row)) * 2048 + seg * 512];
        float sum = 0.f;
        for (int it = 0; it < 64; ++it) {
            short8 h = *(const short8*)(src + it * 8);
#pragma unroll
            for (int u = 0; u < 8; ++u) sum += b2f((ushort_t)h[u]);
        }
        float* scratch = (float*)A_lds;
        scratch[row * 4 + seg] = sum;
        __syncthreads();
        if (tid < 64) {
            float s = scratch[tid * 4] + scratch[tid * 4 + 1]
                    + scratch[tid * 4 + 2] + scratch[tid * 4 + 3];
            vmean[(size_t)b * 512 + n * 64 + tid] = s * (1.0f / (float)S_);
        }
        return;
    }

    const int i0 = tile * 128;
    if (i0 >= xlen_p[b] + 256) return;     // all 128 rows dead -> R never read

    {
        const int srow = tid >> 1, sc0 = (tid & 1) * 32;
        const ushort_t* src = &qrel[((size_t)b * S_ + i0 + srow) * 512 + n * 64 + sc0];
#pragma unroll
        for (int u = 0; u < 4; ++u)
            *(short8*)&A_lds[srow][sc0 + u * 8] = *(const short8*)(src + u * 8);
    }

    const size_t rbase3 = (size_t)(b * NH + n) * S_ * CSL;
    const int srow2 = tid >> 2, sc2 = (tid & 3) * 16;

    short8 pb0, pb1;
    auto issueB = [&](int rc) {
        const ushort_t* src = &krel[(size_t)(rc * 64 + srow2) * 512 + n * 64 + sc2];
        pb0 = *(const short8*)src;
        pb1 = *(const short8*)(src + 8);
    };
    issueB(0);

#pragma unroll 1
    for (int rc = 0; rc < 5; ++rc) {
        __syncthreads();   // A visible (rc==0) / prev chunk's B reads done
        *(short8*)&B_lds[srow2][sc2]     = pb0;
        *(short8*)&B_lds[srow2][sc2 + 8] = pb1;
        if (rc < 4) issueB(rc + 1);
        __syncthreads();

        short8 a[2][2];
#pragma unroll
        for (int mt = 0; mt < 2; ++mt) {
            a[mt][0] = *(const short8*)&A_lds[w * 32 + mt * 16 + l16][quad * 8];
            a[mt][1] = *(const short8*)&A_lds[w * 32 + mt * 16 + l16][quad * 8 + 32];
        }
#pragma unroll
        for (int nt = 0; nt < 4; ++nt) {
            short8 b0 = *(const short8*)&B_lds[nt * 16 + l16][quad * 8];
            short8 b1 = *(const short8*)&B_lds[nt * 16 + l16][quad * 8 + 32];
            const int r = rc * 64 + nt * 16 + l16;
#pragma unroll
            for (int mt = 0; mt < 2; ++mt) {
                f32x4 s = (f32x4){0.f, 0.f, 0.f, 0.f};
                s = __builtin_amdgcn_mfma_f32_16x16x32_bf16(a[mt][0], b0, s, 0, 0, 0);
                s = __builtin_amdgcn_mfma_f32_16x16x32_bf16(a[mt][1], b1, s, 0, 0, 0);
                if (r <= 256) {
#pragma unroll
                    for (int reg = 0; reg < 4; ++reg) {
                        const int ig = i0 + w * 32 + mt * 16 + quad * 4 + reg;
                        const int cslot = (ig & 31) + 256 - r;
                        R3[rbase3 + (size_t)ig * CSL + cslot] = (ushort_t)bf16r(s[reg]);
                    }
                }
            }
        }
    }
}

// ---------------------------------------------------------------------------
// Kernel 5: banded attention via bf16 MFMA.  R13 structure + R3 layout.
// xlen-aware: dead tiles (i0 >= xlen+256) fast-path straight to vmean;
// live tiles only run chunks with jc0 < xlen (later chunks are exactly
// e=0 for every lane: j >= xlen is seq-masked).
// ---------------------------------------------------------------------------
__global__ __launch_bounds__(128) void attn_kernel(
    const ushort_t* __restrict__ qcon, const ushort_t* __restrict__ kbuf,
    const ushort_t* __restrict__ vT, const ushort_t* __restrict__ R3,
    const float* __restrict__ vmean, const int* __restrict__ xlen_p,
    float* __restrict__ out)
{
    const int bx = blockIdx.x;
    const int tile = ((bx & 7) << 3) | (bx >> 3);   // XCD swizzle
    const int n = blockIdx.y, b = blockIdx.z;
    const int i0 = tile * 32;
    const int tid = threadIdx.x, lane = tid & 63, w = tid >> 6;
    const int quad = lane >> 4, l16 = lane & 15;
    const int xlen = xlen_p[b];

    // ---- dead-tile fast path: every row fully masked -> uniform softmax ----
    if (i0 >= xlen + 256) {
        const int row = tid >> 2, c0 = (tid & 3) * 16;
        const float* vm = &vmean[(size_t)b * 512 + n * 64 + c0];
        float* dst = &out[((size_t)b * S_ + i0 + row) * 512 + n * 64 + c0];
#pragma unroll
        for (int u = 0; u < 16; u += 4)
            *(float4*)&dst[u] = *(const float4*)&vm[u];
        return;
    }
    // live chunks: jc0 = i0-256+c*64 < xlen  (>=1 since i0 < xlen+256)
    int nchunk = (xlen - i0 + 256 + 63) >> 6;
    if (nchunk > 5) nchunk = 5;

    __shared__ __align__(16) ushort_t q_lds[32][LP];
    __shared__ __align__(16) ushort_t k_lds[64][LP];
    __shared__ __align__(16) ushort_t vT_lds[64][LP];
    __shared__ __align__(16) ushort_t p_lds[32][LP];
    __shared__ __align__(16) ushort_t Rl_lds[32][LP];

    {
        const int qr = tid >> 2, qc = (tid & 3) * 16;
        const ushort_t* src = &qcon[((size_t)b * S_ + i0 + qr) * 512 + n * 64 + qc];
        *(short8*)&q_lds[qr][qc]     = *(const short8*)src;
        *(short8*)&q_lds[qr][qc + 8] = *(const short8*)(src + 8);
    }

    f32x4 Oa[4];
#pragma unroll
    for (int nt = 0; nt < 4; ++nt) Oa[nt] = (f32x4){0.f, 0.f, 0.f, 0.f};
    float lpart[4] = {};

    const size_t rbase3 = (size_t)(b * NH + n) * S_ * CSL;
    const size_t vTbase = (size_t)((b * NH + n) * 64) * 2048;
    const int srow = tid >> 1, sc0 = (tid & 1) * 32;      // k/vT staging
    const int rrow = tid >> 2, rcol = (tid & 3) * 16;     // R panel staging
    const short8 z8 = {0, 0, 0, 0, 0, 0, 0, 0};

    short8 kr[4], vr[4], kn[4], vn[4];
    short8 rcur[2], rnxt[2];

    auto issue = [&](int c, short8* kd, short8* vd, short8* rd) {
        const int jc0 = i0 - 256 + c * 64;
        const int jg = jc0 + srow;
        const bool okk = (jg >= 0);
        const ushort_t* ks = &kbuf[((size_t)b * S_ + jg) * 512 + n * 64 + sc0];
        const ushort_t* vs = &vT[vTbase + (size_t)srow * 2048 + jc0 + sc0];
#pragma unroll
        for (int u = 0; u < 4; ++u) {
            kd[u] = okk ? *(const short8*)(ks + u * 8) : z8;
            const bool okv = (jc0 + sc0 + u * 8) >= 0;
            vd[u] = okv ? *(const short8*)(vs + u * 8) : z8;
        }
        // R panel: rows i0..i0+31, cols c*64 + rcol .. +15 (contiguous)
        const ushort_t* Rs = &R3[rbase3 + (size_t)(i0 + rrow) * CSL + c * 64 + rcol];
        rd[0] = *(const short8*)Rs;
        rd[1] = *(const short8*)(Rs + 8);
    };

    issue(0, kr, vr, rcur);

#pragma unroll 1
    for (int c = 0; c < nchunk; ++c) {
        const int jc0 = i0 - 256 + c * 64;
        __syncthreads();   // prev-chunk PV reads of k/vT/p + exp reads of Rl done
#pragma unroll
        for (int u = 0; u < 4; ++u) {
            *(short8*)&k_lds[srow][sc0 + u * 8]  = kr[u];
            *(short8*)&vT_lds[srow][sc0 + u * 8] = vr[u];
        }
        *(short8*)&Rl_lds[rrow][rcol]     = rcur[0];
        *(short8*)&Rl_lds[rrow][rcol + 8] = rcur[1];
        if (c + 1 < nchunk) issue(c + 1, kn, vn, rnxt);
        __syncthreads();

        // ---- QK ----
        short8 aq0 = *(const short8*)&q_lds[w * 16 + l16][quad * 8];
        short8 aq1 = *(const short8*)&q_lds[w * 16 + l16][quad * 8 + 32];
        f32x4 Sacc[4];
#pragma unroll
        for (int jt = 0; jt < 4; ++jt) {
            short8 bk0 = *(const short8*)&k_lds[jt * 16 + l16][quad * 8];
            short8 bk1 = *(const short8*)&k_lds[jt * 16 + l16][quad * 8 + 32];
            f32x4 s = (f32x4){0.f, 0.f, 0.f, 0.f};
            s = __builtin_amdgcn_mfma_f32_16x16x32_bf16(aq0, bk0, s, 0, 0, 0);
            s = __builtin_amdgcn_mfma_f32_16x16x32_bf16(aq1, bk1, s, 0, 0, 0);
            Sacc[jt] = s;
        }

        // ---- mask + rel bias (Rl_lds[row][jcol]) + exp; p -> LDS bf16 ----
#pragma unroll
        for (int jt = 0; jt < 4; ++jt) {
#pragma unroll
            for (int reg = 0; reg < 4; ++reg) {
                const int row = w * 16 + quad * 4 + reg;
                const int i = i0 + row;
                const int j = jc0 + jt * 16 + l16;
                const int r = i - j;
                const bool valid = (j >= 0) && (j < xlen) && (r >= 0) && (r <= 256);
                float rvv = b2f(Rl_lds[row][jt * 16 + l16]);
                float e = valid ? __expf(Sacc[jt][reg] + rvv) : 0.f;
                lpart[reg] += e;
                p_lds[row][jt * 16 + l16] = (ushort_t)bf16r(e);
            }
        }
        __syncthreads();

        // ---- PV ----
        short8 ap0 = *(const short8*)&p_lds[w * 16 + l16][quad * 8];
        short8 ap1 = *(const short8*)&p_lds[w * 16 + l16][quad * 8 + 32];
#pragma unroll
        for (int nt = 0; nt < 4; ++nt) {
            short8 bv0 = *(const short8*)&vT_lds[nt * 16 + l16][quad * 8];
            short8 bv1 = *(const short8*)&vT_lds[nt * 16 + l16][quad * 8 + 32];
            Oa[nt] = __builtin_amdgcn_mfma_f32_16x16x32_bf16(ap0, bv0, Oa[nt], 0, 0, 0);
            Oa[nt] = __builtin_amdgcn_mfma_f32_16x16x32_bf16(ap1, bv1, Oa[nt], 0, 0, 0);
        }

        // ---- rotate register sets ----
#pragma unroll
        for (int u = 0; u < 4; ++u) { kr[u] = kn[u]; vr[u] = vn[u]; }
        rcur[0] = rnxt[0]; rcur[1] = rnxt[1];
    }

#pragma unroll
    for (int reg = 0; reg < 4; ++reg) {
#pragma unroll
        for (int off = 1; off < 16; off <<= 1)
            lpart[reg] += __shfl_xor(lpart[reg], off, 64);
    }

#pragma unroll
    for (int reg = 0; reg < 4; ++reg) {
        const int i = i0 + w * 16 + quad * 4 + reg;
        const bool dead = (i >= xlen + 256);
        const float linv = 1.0f / lpart[reg];
#pragma unroll
        for (int nt = 0; nt < 4; ++nt) {
            const int d = n * 64 + nt * 16 + l16;
            float val = dead ? vmean[(size_t)b * 512 + d] : Oa[nt][reg] * linv;
            out[((size_t)b * S_ + i) * 512 + d] = val;
        }
    }
}

// ---------------------------------------------------------------------------
extern "C" void kernel_launch(void* const* d_in, const int* in_sizes, int n_in,
                              void* d_out, int out_size, void* d_ws, size_t ws_size,
                              hipStream_t stream) {
    const float* x     = (const float*)d_in[0];
    const float* Wq    = (const float*)d_in[1];
    const float* b_con = (const float*)d_in[2];
    const float* b_rel = (const float*)d_in[3];
    const float* Wk    = (const float*)d_in[4];
    const float* Wkr   = (const float*)d_in[5];
    const float* Wv    = (const float*)d_in[6];
    const float* bv    = (const float*)d_in[7];
    const int*   xlen  = (const int*)d_in[8];
    float* out = (float*)d_out;

    float* ws = (float*)d_ws;
    float* vmean = ws;                       // 1024 fp32
    ushort_t* ub   = (ushort_t*)(vmean + 1024);
    ushort_t* R3   = ub;                     // 16*2048*320 bf16 = 21 MB
    ushort_t* qcon = R3   + 10485760;
    ushort_t* kbuf = qcon + 2097152;
    ushort_t* vT   = kbuf + 2097152;         // 1024 x 2048 bf16
    ushort_t* qrel = vT   + 2097152;
    ushort_t* xb16 = qrel + 2097152;         // 4096*512 bf16
    ushort_t* krel = xb16 + 2097152;         // 384*512 bf16
    ushort_t* pos  = krel + 196608;          // 384*512 bf16
    ushort_t* WTq  = pos  + 196608;          // 512*512 bf16 each
    ushort_t* WTk  = WTq + 262144;
    ushort_t* WTv  = WTk + 262144;
    ushort_t* WTkr = WTv + 262144;

    prep_kernel<<<dim3(8, 8, 6), 256, 0, stream>>>(x, Wq, Wk, Wv, Wkr,
                                                   WTq, WTk, WTv, WTkr, pos, xb16);
    qkv_gemm<<<dim3(32, 25), 256, 0, stream>>>(xb16, WTq, WTk, WTv, pos, WTkr,
                                               b_con, b_rel, bv, xlen,
                                               qcon, qrel, kbuf, vT, krel);
    rel_gemm<<<dim3(17, 8, 2), 256, 0, stream>>>(qrel, krel, vT, xlen, R3, vmean);
    attn_kernel<<<dim3(64, 8, 2), 128, 0, stream>>>(qcon, kbuf, vT, R3, vmean,
                                                    xlen, out);
}